// Round 7
// baseline (166.392 us; speedup 1.0000x reference)
//
#include <hip/hip_runtime.h>
#include <hip/hip_bf16.h>
#include <cstddef>

#define NHEADS 9
#define D 32
#define SQ 4096
#define ZSPLIT 4
#define MBLK (SQ / ZSPLIT)     // 1024 m per block
#define CHUNKS (MBLK / 64)     // 16 chunks of 64 m
#define KROW 40                // K LDS row stride (halfwords): 80 B (balanced b128 banks)
#define VROW 70                // V LDS row stride (halfwords): 140 B (conflict-free scatter)

typedef __attribute__((ext_vector_type(8))) short bf16x8;
typedef __attribute__((ext_vector_type(4))) short bf16x4;
typedef __attribute__((ext_vector_type(4))) float f32x4;

__device__ __forceinline__ unsigned int f2bf(float f) {
    unsigned int u = __float_as_uint(f);
    u += 0x7fffu + ((u >> 16) & 1u);
    return u >> 16;
}

__device__ __forceinline__ unsigned int cvt_pk_bf16(float a, float b) {
#if __has_builtin(__builtin_amdgcn_cvt_pk_bf16_f32)
    typedef __attribute__((ext_vector_type(2))) __bf16 bf2;
    union { bf2 v; unsigned int u; } cv;
    cv.v = __builtin_amdgcn_cvt_pk_bf16_f32(a, b);
    return cv.u;
#else
    return (f2bf(b) << 16) | f2bf(a);
#endif
}

// relu + pack 4 f32 scores (threshold already subtracted via MFMA C-operand)
__device__ __forceinline__ bf16x4 relu_pack(f32x4 st) {
    float a0 = fmaxf(st[0], 0.0f);
    float a1 = fmaxf(st[1], 0.0f);
    float a2 = fmaxf(st[2], 0.0f);
    float a3 = fmaxf(st[3], 0.0f);
    union { unsigned int u[2]; bf16x4 v; } r;
    r.u[0] = cvt_pk_bf16(a0, a1);
    r.u[1] = cvt_pk_bf16(a2, a3);
    return r.v;
}

// ---------------------------------------------------------------------------
// Prep: bilinear upsample (32->64, half-pixel) + 1x1 convs -> Q,K,V (bf16) + t
// One thread per (bh, n, 8-d-group). ALL stores contiguous uint4.
// Also zeroes the 'of' accumulator (replaces a separate memset dispatch).
// Q: [bh][n][d]   K: [bh][m][d]   V: [bh][m][d]
// ---------------------------------------------------------------------------
__global__ __launch_bounds__(256) void prep_kernel(
    const float* __restrict__ x2, const float* __restrict__ x1,
    const float* __restrict__ feat1,
    const float* __restrict__ Wq, const float* __restrict__ bq,
    const float* __restrict__ Wk, const float* __restrict__ bk,
    const float* __restrict__ Wv, const float* __restrict__ bv,
    const float* __restrict__ Wt, const float* __restrict__ bt,
    unsigned short* __restrict__ Qb, unsigned short* __restrict__ Kb,
    unsigned short* __restrict__ Vb, float* __restrict__ tbuf,
    float* __restrict__ of)
{
    int idx = blockIdx.x * blockDim.x + threadIdx.x;   // 0 .. 2*9*4096*4-1
    if (idx < 2 * 4 * SQ) of[idx] = 0.0f;              // zero accumulator
    int g  = idx & 3;                 // d-group: d = g*8 .. g*8+7
    int n  = (idx >> 2) & (SQ - 1);
    int bh = idx >> 14;               // 0..17
    int h  = bh % NHEADS;
    int b  = bh / NHEADS;

    float xs0 = x2[((size_t)b * 3 + 0) * SQ + n];
    float xs1 = x2[((size_t)b * 3 + 1) * SQ + n];
    float xs2 = x2[((size_t)b * 3 + 2) * SQ + n];
    float ys0 = x1[((size_t)b * 3 + 0) * SQ + n];
    float ys1 = x1[((size_t)b * 3 + 1) * SQ + n];
    float ys2 = x1[((size_t)b * 3 + 2) * SQ + n];

    // bilinear upsample coords: src = i*0.5 - 0.25 (half-pixel, align_corners=False)
    int yy = n >> 6, xx = n & 63;
    int jy = yy >> 1, jx = xx >> 1;
    int j0, j1, i0, i1; float wy0, wy1, wx0, wx1;
    if (yy & 1) { j0 = jy; j1 = (jy < 31) ? jy + 1 : 31; wy0 = 0.75f; wy1 = 0.25f; }
    else        { j0 = (jy > 0) ? jy - 1 : 0; j1 = jy;   wy0 = 0.25f; wy1 = 0.75f; }
    if (xx & 1) { i0 = jx; i1 = (jx < 31) ? jx + 1 : 31; wx0 = 0.75f; wx1 = 0.25f; }
    else        { i0 = (jx > 0) ? jx - 1 : 0; i1 = jx;   wx0 = 0.25f; wx1 = 0.75f; }

    float fu[4];
#pragma unroll
    for (int c = 0; c < 4; ++c) {
        const float* f = feat1 + ((size_t)b * 4 + c) * 1024;
        fu[c] = wy0 * (wx0 * f[j0 * 32 + i0] + wx1 * f[j0 * 32 + i1]) +
                wy1 * (wx0 * f[j1 * 32 + i0] + wx1 * f[j1 * 32 + i1]);
    }

    const int d0 = g * 8;
    unsigned int qp[4], kp[4], vp[4];
    float tpart = 0.0f;
#pragma unroll
    for (int j = 0; j < 8; ++j) {
        int d = d0 + j, hd = h * D + d;
        float q = bq[hd] + Wq[hd * 3] * xs0 + Wq[hd * 3 + 1] * xs1 + Wq[hd * 3 + 2] * xs2;
        float k = bk[hd] + Wk[hd * 3] * ys0 + Wk[hd * 3 + 1] * ys1 + Wk[hd * 3 + 2] * ys2;
        float v = bv[hd] + Wv[hd * 4] * fu[0] + Wv[hd * 4 + 1] * fu[1] +
                  Wv[hd * 4 + 2] * fu[2] + Wv[hd * 4 + 3] * fu[3];
        tpart += q * Wt[d];
        unsigned int qb_ = f2bf(q), kb_ = f2bf(k), vb_ = f2bf(v);
        if (j & 1) { qp[j >> 1] |= qb_ << 16; kp[j >> 1] |= kb_ << 16; vp[j >> 1] |= vb_ << 16; }
        else       { qp[j >> 1]  = qb_;       kp[j >> 1]  = kb_;       vp[j >> 1]  = vb_; }
    }
    // reduce threshold partial over the 4-lane d-group
    tpart += __shfl_xor(tpart, 1);
    tpart += __shfl_xor(tpart, 2);
    if (g == 0) tbuf[(size_t)bh * SQ + n] = tpart + bt[0];

    size_t base = ((size_t)bh * SQ + n) * D + d0;
    *(uint4*)(Qb + base) = make_uint4(qp[0], qp[1], qp[2], qp[3]);
    *(uint4*)(Kb + base) = make_uint4(kp[0], kp[1], kp[2], kp[3]);
    *(uint4*)(Vb + base) = make_uint4(vp[0], vp[1], vp[2], vp[3]);
}

// ---------------------------------------------------------------------------
// Attention: block = (bh, 256 n, 1024 m); wave = 64 n (4 Q-tiles).
// Threshold folded into the QK MFMA C-operand (acc init = -t*sqrt(32)),
// 1/(sqrt(32)*3000) deferred to the epilogue -> relu is a bare fmax.
// Per 64-m chunk: cooperative staging of K[64][32] (contig uint4) and
// V transposed to [d][m] (scatter, VROW=70 -> conflict-free banks).
// Per 16-m sub-iter: 1x ds_read_b128 (K) + 2x ds_read_b64 (V) feed
// 4x mfma_16x16x32 (QK) + 8x mfma_16x16x16 (PV) across the 4 Q-tiles.
// ---------------------------------------------------------------------------
__global__ __launch_bounds__(256, 4) void attn_kernel(
    const unsigned short* __restrict__ Qb,
    const unsigned short* __restrict__ Kb,
    const unsigned short* __restrict__ Vb,
    const float* __restrict__ tbuf,
    const float* __restrict__ Wp,
    float* __restrict__ of)
{
    __shared__ __align__(16) unsigned short Ks[64 * KROW];  // [m][d]
    __shared__ __align__(16) unsigned short Vs[32 * VROW];  // [d][m]

    const int bh   = blockIdx.y;
    const int h    = bh % NHEADS;
    const int b    = bh / NHEADS;
    const int n0   = blockIdx.x * 256;
    const int mc0  = blockIdx.z * MBLK;
    const int tid  = threadIdx.x;
    const int wave = tid >> 6;
    const int lane = tid & 63;
    const int l15  = lane & 15;
    const int quad = lane >> 4;

    const int nw = n0 + wave * 64;

    // Q as B-fragment: B[d=quad*8+j][n=l15], 4 tiles at n offsets 0/16/32/48
    const unsigned short* qbase = Qb + ((size_t)bh * SQ + nw + l15) * D + quad * 8;
    bf16x8 qfA = *(const bf16x8*)(qbase);
    bf16x8 qfB = *(const bf16x8*)(qbase + 16 * D);
    bf16x8 qfC = *(const bf16x8*)(qbase + 32 * D);
    bf16x8 qfD = *(const bf16x8*)(qbase + 48 * D);

    const float SQRT32 = 5.656854249492381f;
    const float* tb = tbuf + (size_t)bh * SQ + nw + l15;
    float TA = tb[0]  * SQRT32;
    float TB = tb[16] * SQRT32;
    float TC = tb[32] * SQRT32;
    float TD = tb[48] * SQRT32;
    const f32x4 ciA = {-TA, -TA, -TA, -TA};
    const f32x4 ciB = {-TB, -TB, -TB, -TB};
    const f32x4 ciC = {-TC, -TC, -TC, -TC};
    const f32x4 ciD = {-TD, -TD, -TD, -TD};

    const uint4* Kg4 = (const uint4*)(Kb + (size_t)bh * SQ * D);
    const uint4* Vg4 = (const uint4*)(Vb + (size_t)bh * SQ * D);

    // staging: 16B per thread of the 4KB chunk
    const int krow = tid >> 2;            // m row 0..63
    const int kcol = (tid & 3) * 8;       // halfword col in 32-d row
    unsigned short* kdst = Ks + krow * KROW + kcol;
    unsigned short* vdst = Vs + kcol * VROW + krow;   // transpose scatter

    f32x4 accAl = {0.f,0.f,0.f,0.f}, accAh = {0.f,0.f,0.f,0.f};
    f32x4 accBl = {0.f,0.f,0.f,0.f}, accBh = {0.f,0.f,0.f,0.f};
    f32x4 accCl = {0.f,0.f,0.f,0.f}, accCh = {0.f,0.f,0.f,0.f};
    f32x4 accDl = {0.f,0.f,0.f,0.f}, accDh = {0.f,0.f,0.f,0.f};

    uint4 kreg = Kg4[(size_t)mc0 * 4 + tid];
    uint4 vreg = Vg4[(size_t)mc0 * 4 + tid];

    for (int c = 0; c < CHUNKS; ++c) {
        __syncthreads();   // previous compute done
        *(uint4*)kdst = kreg;
        {
            union { uint4 u; unsigned short s[8]; } vv; vv.u = vreg;
#pragma unroll
            for (int j = 0; j < 8; ++j) vdst[j * VROW] = vv.s[j];
        }
        // prefetch next chunk (last iter over-reads into adjacent workspace)
        kreg = Kg4[(size_t)(mc0 + (c + 1) * 64) * 4 + tid];
        vreg = Vg4[(size_t)(mc0 + (c + 1) * 64) * 4 + tid];
        __syncthreads();   // staged data visible

#pragma unroll
        for (int s = 0; s < 4; ++s) {
            bf16x8 kf = *(const bf16x8*)(Ks + (s * 16 + l15) * KROW + quad * 8);
            bf16x4 va = *(const bf16x4*)(Vs + l15 * VROW + s * 16 + quad * 4);
            bf16x4 vb = *(const bf16x4*)(Vs + (l15 + 16) * VROW + s * 16 + quad * 4);

            f32x4 stA = __builtin_amdgcn_mfma_f32_16x16x32_bf16(kf, qfA, ciA, 0, 0, 0);
            f32x4 stB = __builtin_amdgcn_mfma_f32_16x16x32_bf16(kf, qfB, ciB, 0, 0, 0);
            f32x4 stC = __builtin_amdgcn_mfma_f32_16x16x32_bf16(kf, qfC, ciC, 0, 0, 0);
            f32x4 stD = __builtin_amdgcn_mfma_f32_16x16x32_bf16(kf, qfD, ciD, 0, 0, 0);

            bf16x4 pA = relu_pack(stA);
            bf16x4 pB = relu_pack(stB);
            bf16x4 pC = relu_pack(stC);
            bf16x4 pD = relu_pack(stD);

            accAl = __builtin_amdgcn_mfma_f32_16x16x16bf16_1k(va, pA, accAl, 0, 0, 0);
            accAh = __builtin_amdgcn_mfma_f32_16x16x16bf16_1k(vb, pA, accAh, 0, 0, 0);
            accBl = __builtin_amdgcn_mfma_f32_16x16x16bf16_1k(va, pB, accBl, 0, 0, 0);
            accBh = __builtin_amdgcn_mfma_f32_16x16x16bf16_1k(vb, pB, accBh, 0, 0, 0);
            accCl = __builtin_amdgcn_mfma_f32_16x16x16bf16_1k(va, pC, accCl, 0, 0, 0);
            accCh = __builtin_amdgcn_mfma_f32_16x16x16bf16_1k(vb, pC, accCh, 0, 0, 0);
            accDl = __builtin_amdgcn_mfma_f32_16x16x16bf16_1k(va, pD, accDl, 0, 0, 0);
            accDh = __builtin_amdgcn_mfma_f32_16x16x16bf16_1k(vb, pD, accDh, 0, 0, 0);
        }
    }

    // lane holds out^T[d = quad*4+r (lo) / 16+... (hi)][n] (x 1/s1 scale).
    // Project 288->4 with Wp, apply deferred s1, reduce quads, atomics.
    const float s1 = 5.892556509887896e-05f;   // 1/(sqrt(32)*3000)
    const float* wph = Wp + h * D + quad * 4;
#pragma unroll
    for (int o = 0; o < 4; ++o) {
        float cA = 0.f, cB = 0.f, cC = 0.f, cD = 0.f;
#pragma unroll
        for (int r = 0; r < 4; ++r) {
            float wlo = wph[o * 288 + r], whi = wph[o * 288 + 16 + r];
            cA += accAl[r] * wlo + accAh[r] * whi;
            cB += accBl[r] * wlo + accBh[r] * whi;
            cC += accCl[r] * wlo + accCh[r] * whi;
            cD += accDl[r] * wlo + accDh[r] * whi;
        }
        cA += __shfl_xor(cA, 16); cA += __shfl_xor(cA, 32);
        cB += __shfl_xor(cB, 16); cB += __shfl_xor(cB, 32);
        cC += __shfl_xor(cC, 16); cC += __shfl_xor(cC, 32);
        cD += __shfl_xor(cD, 16); cD += __shfl_xor(cD, 32);
        if (quad == 0) {
            float* ob = &of[((size_t)b * 4 + o) * SQ + nw + l15];
            atomicAdd(ob,      cA * s1);
            atomicAdd(ob + 16, cB * s1);
            atomicAdd(ob + 32, cC * s1);
            atomicAdd(ob + 48, cD * s1);
        }
    }
}

// ---------------------------------------------------------------------------
// Final: 2x2-mean downsample + bias + residual; both tuple outputs.
// ---------------------------------------------------------------------------
__global__ void final_kernel(const float* __restrict__ of,
                             const float* __restrict__ sff,
                             const float* __restrict__ bp,
                             float* __restrict__ dout)
{
    int tid = blockIdx.x * blockDim.x + threadIdx.x;  // 0..8191
    if (tid >= 8192) return;
    int i  = tid & 31;
    int jj = (tid >> 5) & 31;
    int bo = tid >> 10;
    int o  = bo & 3;
    const float* src = of + (size_t)bo * SQ;
    int y = jj * 2, x = i * 2;
    float dval = 0.25f * (src[y * 64 + x] + src[y * 64 + x + 1] +
                          src[(y + 1) * 64 + x] + src[(y + 1) * 64 + x + 1]) + bp[o];
    dout[tid]        = sff[tid] + dval;
    dout[8192 + tid] = dval;
}

extern "C" void kernel_launch(void* const* d_in, const int* in_sizes, int n_in,
                              void* d_out, int out_size, void* d_ws, size_t ws_size,
                              hipStream_t stream)
{
    const float* second_frame = (const float*)d_in[0];
    const float* first_frame  = (const float*)d_in[1];
    const float* sff          = (const float*)d_in[2];
    const float* ffa          = (const float*)d_in[3];
    const float* Wq = (const float*)d_in[4];
    const float* bq = (const float*)d_in[5];
    const float* Wk = (const float*)d_in[6];
    const float* bk = (const float*)d_in[7];
    const float* Wv = (const float*)d_in[8];
    const float* bv = (const float*)d_in[9];
    const float* Wp = (const float*)d_in[10];
    const float* bp = (const float*)d_in[11];
    const float* Wt = (const float*)d_in[12];
    const float* bt = (const float*)d_in[13];
    float* out = (float*)d_out;

    char* ws = (char*)d_ws;
    const size_t QKV = (size_t)2 * NHEADS * SQ * D * sizeof(unsigned short);
    unsigned short* Qb = (unsigned short*)ws;
    unsigned short* Kb = (unsigned short*)(ws + QKV);
    unsigned short* Vb = (unsigned short*)(ws + 2 * QKV);
    float* tbuf = (float*)(ws + 3 * QKV);
    float* of   = (float*)(ws + 3 * QKV + (size_t)2 * NHEADS * SQ * sizeof(float));

    prep_kernel<<<1152, 256, 0, stream>>>(second_frame, first_frame, ffa,
                                          Wq, bq, Wk, bk, Wv, bv, Wt, bt,
                                          Qb, Kb, Vb, tbuf, of);
    dim3 ag(16, 18, ZSPLIT);
    attn_kernel<<<ag, 256, 0, stream>>>(Qb, Kb, Vb, tbuf, Wp, of);
    final_kernel<<<32, 256, 0, stream>>>(of, sff, bp, out);
}

// Round 8
// 152.524 us; speedup vs baseline: 1.0909x; 1.0909x over previous
//
#include <hip/hip_runtime.h>
#include <hip/hip_bf16.h>
#include <cstddef>

#define NHEADS 9
#define D 32
#define SQ 4096
#define ZSPLIT 8
#define MBLK (SQ / ZSPLIT)     // 512 m per block
#define CHUNKS (MBLK / 64)     // 8 chunks of 64 m
#define KROW 40                // K LDS row stride (halfwords): balanced b128 banks
#define VROW 72                // V LDS row stride (halfwords): balanced b128 banks

typedef __attribute__((ext_vector_type(8))) short bf16x8;
typedef __attribute__((ext_vector_type(4))) short bf16x4;
typedef __attribute__((ext_vector_type(4))) float f32x4;

__device__ __forceinline__ unsigned int f2bf(float f) {
    unsigned int u = __float_as_uint(f);
    u += 0x7fffu + ((u >> 16) & 1u);
    return u >> 16;
}

__device__ __forceinline__ unsigned int cvt_pk_bf16(float a, float b) {
#if __has_builtin(__builtin_amdgcn_cvt_pk_bf16_f32)
    typedef __attribute__((ext_vector_type(2))) __bf16 bf2;
    union { bf2 v; unsigned int u; } cv;
    cv.v = __builtin_amdgcn_cvt_pk_bf16_f32(a, b);
    return cv.u;
#else
    return (f2bf(b) << 16) | f2bf(a);
#endif
}

// relu + pack 4 f32 scores (threshold pre-subtracted via MFMA C-operand)
__device__ __forceinline__ bf16x4 relu_pack(f32x4 st) {
    float a0 = fmaxf(st[0], 0.0f);
    float a1 = fmaxf(st[1], 0.0f);
    float a2 = fmaxf(st[2], 0.0f);
    float a3 = fmaxf(st[3], 0.0f);
    union { unsigned int u[2]; bf16x4 v; } r;
    r.u[0] = cvt_pk_bf16(a0, a1);
    r.u[1] = cvt_pk_bf16(a2, a3);
    return r.v;
}

// ---------------------------------------------------------------------------
// Prep: bilinear upsample (32->64, half-pixel) + 1x1 convs -> Q,K,V (bf16) + t
// One thread per (bh, n, 8-d-group). Q/K contiguous uint4; V transposed to
// [bh][d][m] (8 u16 stores) so attn stages it without a scatter.
// Also zeroes the 'of' accumulator.
// ---------------------------------------------------------------------------
__global__ __launch_bounds__(256) void prep_kernel(
    const float* __restrict__ x2, const float* __restrict__ x1,
    const float* __restrict__ feat1,
    const float* __restrict__ Wq, const float* __restrict__ bq,
    const float* __restrict__ Wk, const float* __restrict__ bk,
    const float* __restrict__ Wv, const float* __restrict__ bv,
    const float* __restrict__ Wt, const float* __restrict__ bt,
    unsigned short* __restrict__ Qb, unsigned short* __restrict__ Kb,
    unsigned short* __restrict__ Vt, float* __restrict__ tbuf,
    float* __restrict__ of)
{
    int idx = blockIdx.x * blockDim.x + threadIdx.x;   // 0 .. 2*9*4096*4-1
    if (idx < 2 * 4 * SQ) of[idx] = 0.0f;              // zero accumulator
    int g  = idx & 3;                 // d-group: d = g*8 .. g*8+7
    int n  = (idx >> 2) & (SQ - 1);
    int bh = idx >> 14;               // 0..17
    int h  = bh % NHEADS;
    int b  = bh / NHEADS;

    float xs0 = x2[((size_t)b * 3 + 0) * SQ + n];
    float xs1 = x2[((size_t)b * 3 + 1) * SQ + n];
    float xs2 = x2[((size_t)b * 3 + 2) * SQ + n];
    float ys0 = x1[((size_t)b * 3 + 0) * SQ + n];
    float ys1 = x1[((size_t)b * 3 + 1) * SQ + n];
    float ys2 = x1[((size_t)b * 3 + 2) * SQ + n];

    // bilinear upsample coords: src = i*0.5 - 0.25 (half-pixel)
    int yy = n >> 6, xx = n & 63;
    int jy = yy >> 1, jx = xx >> 1;
    int j0, j1, i0, i1; float wy0, wy1, wx0, wx1;
    if (yy & 1) { j0 = jy; j1 = (jy < 31) ? jy + 1 : 31; wy0 = 0.75f; wy1 = 0.25f; }
    else        { j0 = (jy > 0) ? jy - 1 : 0; j1 = jy;   wy0 = 0.25f; wy1 = 0.75f; }
    if (xx & 1) { i0 = jx; i1 = (jx < 31) ? jx + 1 : 31; wx0 = 0.75f; wx1 = 0.25f; }
    else        { i0 = (jx > 0) ? jx - 1 : 0; i1 = jx;   wx0 = 0.25f; wx1 = 0.75f; }

    float fu[4];
#pragma unroll
    for (int c = 0; c < 4; ++c) {
        const float* f = feat1 + ((size_t)b * 4 + c) * 1024;
        fu[c] = wy0 * (wx0 * f[j0 * 32 + i0] + wx1 * f[j0 * 32 + i1]) +
                wy1 * (wx0 * f[j1 * 32 + i0] + wx1 * f[j1 * 32 + i1]);
    }

    const int d0 = g * 8;
    unsigned int qp[4], kp[4];
    float tpart = 0.0f;
#pragma unroll
    for (int j = 0; j < 8; ++j) {
        int d = d0 + j, hd = h * D + d;
        float q = bq[hd] + Wq[hd * 3] * xs0 + Wq[hd * 3 + 1] * xs1 + Wq[hd * 3 + 2] * xs2;
        float k = bk[hd] + Wk[hd * 3] * ys0 + Wk[hd * 3 + 1] * ys1 + Wk[hd * 3 + 2] * ys2;
        float v = bv[hd] + Wv[hd * 4] * fu[0] + Wv[hd * 4 + 1] * fu[1] +
                  Wv[hd * 4 + 2] * fu[2] + Wv[hd * 4 + 3] * fu[3];
        tpart += q * Wt[d];
        unsigned int qb_ = f2bf(q), kb_ = f2bf(k);
        if (j & 1) { qp[j >> 1] |= qb_ << 16; kp[j >> 1] |= kb_ << 16; }
        else       { qp[j >> 1]  = qb_;       kp[j >> 1]  = kb_; }
        Vt[((size_t)bh * D + d) * SQ + n] = (unsigned short)f2bf(v);
    }
    // reduce threshold partial over the 4-lane d-group
    tpart += __shfl_xor(tpart, 1);
    tpart += __shfl_xor(tpart, 2);
    if (g == 0) tbuf[(size_t)bh * SQ + n] = tpart + bt[0];

    size_t base = ((size_t)bh * SQ + n) * D + d0;
    *(uint4*)(Qb + base) = make_uint4(qp[0], qp[1], qp[2], qp[3]);
    *(uint4*)(Kb + base) = make_uint4(kp[0], kp[1], kp[2], kp[3]);
}

// ---------------------------------------------------------------------------
// Attention: block = (bh, 256 n, 512 m); wave = 64 n (4 Q-tiles).
// Grid 16x18x8 = 2304 blocks (the empirically-required concurrency).
// K staged with PERMUTED rows: slot(m) interleaves by m&4 so that
// concat(reluQK(rows 0-15), reluQK(rows 16-31)) is exactly the B-fragment
// of mfma_16x16x32 -> PV runs at K=32 (half the PV MFMA instructions).
// V staged from global [d][m] with a straight uint4 copy (no scatter).
// KROW=40 / VROW=72: every LDS access pattern is bank-balanced (min cycles).
// Threshold folded into the QK C-operand; 1/(sqrt(32)*3000) deferred.
// ---------------------------------------------------------------------------
__global__ __launch_bounds__(256, 4) void attn_kernel(
    const unsigned short* __restrict__ Qb,
    const unsigned short* __restrict__ Kb,
    const unsigned short* __restrict__ Vt,
    const float* __restrict__ tbuf,
    const float* __restrict__ Wp,
    float* __restrict__ of)
{
    __shared__ __align__(16) unsigned short Ks[64 * KROW];  // [slot][d] 5120 B
    __shared__ __align__(16) unsigned short Vs[32 * VROW];  // [d][m]    4608 B

    const int bh   = blockIdx.y;
    const int h    = bh % NHEADS;
    const int b    = bh / NHEADS;
    const int n0   = blockIdx.x * 256;
    const int mc0  = blockIdx.z * MBLK;
    const int tid  = threadIdx.x;
    const int wave = tid >> 6;
    const int lane = tid & 63;
    const int l15  = lane & 15;
    const int quad = lane >> 4;

    const int nw = n0 + wave * 64;

    // Q as B-fragment: B[d=quad*8+j][n=l15], 4 tiles at n offsets 0/16/32/48
    const unsigned short* qbase = Qb + ((size_t)bh * SQ + nw + l15) * D + quad * 8;
    bf16x8 qfA = *(const bf16x8*)(qbase);
    bf16x8 qfB = *(const bf16x8*)(qbase + 16 * D);
    bf16x8 qfC = *(const bf16x8*)(qbase + 32 * D);
    bf16x8 qfD = *(const bf16x8*)(qbase + 48 * D);

    const float SQRT32 = 5.656854249492381f;
    const float* tb = tbuf + (size_t)bh * SQ + nw + l15;
    float TA = tb[0]  * SQRT32;
    float TB = tb[16] * SQRT32;
    float TC = tb[32] * SQRT32;
    float TD = tb[48] * SQRT32;
    const f32x4 ciA = {-TA, -TA, -TA, -TA};
    const f32x4 ciB = {-TB, -TB, -TB, -TB};
    const f32x4 ciC = {-TC, -TC, -TC, -TC};
    const f32x4 ciD = {-TD, -TD, -TD, -TD};

    const uint4* Kg4 = (const uint4*)(Kb + (size_t)bh * SQ * D);
    const uint4* Vg4 = (const uint4*)(Vt + (size_t)bh * D * SQ);

    // K staging: krow = m-local 0..63 -> permuted slot; 16B per thread.
    const int krow = tid >> 2;
    const int kcol = (tid & 3) * 8;
    const int kslot = (krow & 32) + 4 * ((krow >> 3) & 3) + (krow & 3) + ((krow & 4) << 2);
    unsigned short* kdst = Ks + kslot * KROW + kcol;
    // V staging: straight copy of V[d][m-chunk]; d = tid>>3, m-col = (tid&7)*8
    const int vd = tid >> 3;
    const int vm = (tid & 7) * 8;
    unsigned short* vdst = Vs + vd * VROW + vm;
    const int vgbase = vd * (SQ / 8) + (mc0 >> 3) + (tid & 7);

    f32x4 accAl = {0.f,0.f,0.f,0.f}, accAh = {0.f,0.f,0.f,0.f};
    f32x4 accBl = {0.f,0.f,0.f,0.f}, accBh = {0.f,0.f,0.f,0.f};
    f32x4 accCl = {0.f,0.f,0.f,0.f}, accCh = {0.f,0.f,0.f,0.f};
    f32x4 accDl = {0.f,0.f,0.f,0.f}, accDh = {0.f,0.f,0.f,0.f};

    uint4 kreg = Kg4[(size_t)mc0 * 4 + tid];
    uint4 vreg = Vg4[vgbase];

    for (int c = 0; c < CHUNKS; ++c) {
        __syncthreads();   // previous compute done
        *(uint4*)kdst = kreg;
        *(uint4*)vdst = vreg;
        // prefetch next chunk (last iter over-reads into adjacent workspace)
        kreg = Kg4[(size_t)(mc0 + (c + 1) * 64) * 4 + tid];
        vreg = Vg4[vgbase + (c + 1) * 8];
        __syncthreads();   // staged data visible

#pragma unroll
        for (int g32 = 0; g32 < 2; ++g32) {
            const unsigned short* kbase = Ks + g32 * 32 * KROW;
            bf16x8 kf1 = *(const bf16x8*)(kbase + l15 * KROW + quad * 8);
            bf16x8 kf2 = *(const bf16x8*)(kbase + (16 + l15) * KROW + quad * 8);
            bf16x8 vlo = *(const bf16x8*)(Vs + l15 * VROW + g32 * 32 + quad * 8);
            bf16x8 vhi = *(const bf16x8*)(Vs + (l15 + 16) * VROW + g32 * 32 + quad * 8);

            f32x4 sA1 = __builtin_amdgcn_mfma_f32_16x16x32_bf16(kf1, qfA, ciA, 0, 0, 0);
            f32x4 sA2 = __builtin_amdgcn_mfma_f32_16x16x32_bf16(kf2, qfA, ciA, 0, 0, 0);
            f32x4 sB1 = __builtin_amdgcn_mfma_f32_16x16x32_bf16(kf1, qfB, ciB, 0, 0, 0);
            f32x4 sB2 = __builtin_amdgcn_mfma_f32_16x16x32_bf16(kf2, qfB, ciB, 0, 0, 0);
            f32x4 sC1 = __builtin_amdgcn_mfma_f32_16x16x32_bf16(kf1, qfC, ciC, 0, 0, 0);
            f32x4 sC2 = __builtin_amdgcn_mfma_f32_16x16x32_bf16(kf2, qfC, ciC, 0, 0, 0);
            f32x4 sD1 = __builtin_amdgcn_mfma_f32_16x16x32_bf16(kf1, qfD, ciD, 0, 0, 0);
            f32x4 sD2 = __builtin_amdgcn_mfma_f32_16x16x32_bf16(kf2, qfD, ciD, 0, 0, 0);

            bf16x4 pA1 = relu_pack(sA1), pA2 = relu_pack(sA2);
            bf16x4 pB1 = relu_pack(sB1), pB2 = relu_pack(sB2);
            bf16x4 pC1 = relu_pack(sC1), pC2 = relu_pack(sC2);
            bf16x4 pD1 = relu_pack(sD1), pD2 = relu_pack(sD2);
            bf16x8 pA = __builtin_shufflevector(pA1, pA2, 0,1,2,3,4,5,6,7);
            bf16x8 pB = __builtin_shufflevector(pB1, pB2, 0,1,2,3,4,5,6,7);
            bf16x8 pC = __builtin_shufflevector(pC1, pC2, 0,1,2,3,4,5,6,7);
            bf16x8 pD = __builtin_shufflevector(pD1, pD2, 0,1,2,3,4,5,6,7);

            accAl = __builtin_amdgcn_mfma_f32_16x16x32_bf16(vlo, pA, accAl, 0, 0, 0);
            accAh = __builtin_amdgcn_mfma_f32_16x16x32_bf16(vhi, pA, accAh, 0, 0, 0);
            accBl = __builtin_amdgcn_mfma_f32_16x16x32_bf16(vlo, pB, accBl, 0, 0, 0);
            accBh = __builtin_amdgcn_mfma_f32_16x16x32_bf16(vhi, pB, accBh, 0, 0, 0);
            accCl = __builtin_amdgcn_mfma_f32_16x16x32_bf16(vlo, pC, accCl, 0, 0, 0);
            accCh = __builtin_amdgcn_mfma_f32_16x16x32_bf16(vhi, pC, accCh, 0, 0, 0);
            accDl = __builtin_amdgcn_mfma_f32_16x16x32_bf16(vlo, pD, accDl, 0, 0, 0);
            accDh = __builtin_amdgcn_mfma_f32_16x16x32_bf16(vhi, pD, accDh, 0, 0, 0);
        }
    }

    // lane holds out^T[d = quad*4+r (lo) / 16+... (hi)][n] (x sqrt(32)*3000).
    // Project 288->4 with Wp, apply deferred scale, reduce quads, atomics.
    const float s1 = 5.892556509887896e-05f;   // 1/(sqrt(32)*3000)
    const float* wph = Wp + h * D + quad * 4;
#pragma unroll
    for (int o = 0; o < 4; ++o) {
        float cA = 0.f, cB = 0.f, cC = 0.f, cD = 0.f;
#pragma unroll
        for (int r = 0; r < 4; ++r) {
            float wlo = wph[o * 288 + r], whi = wph[o * 288 + 16 + r];
            cA += accAl[r] * wlo + accAh[r] * whi;
            cB += accBl[r] * wlo + accBh[r] * whi;
            cC += accCl[r] * wlo + accCh[r] * whi;
            cD += accDl[r] * wlo + accDh[r] * whi;
        }
        cA += __shfl_xor(cA, 16); cA += __shfl_xor(cA, 32);
        cB += __shfl_xor(cB, 16); cB += __shfl_xor(cB, 32);
        cC += __shfl_xor(cC, 16); cC += __shfl_xor(cC, 32);
        cD += __shfl_xor(cD, 16); cD += __shfl_xor(cD, 32);
        if (quad == 0) {
            float* ob = &of[((size_t)b * 4 + o) * SQ + nw + l15];
            atomicAdd(ob,      cA * s1);
            atomicAdd(ob + 16, cB * s1);
            atomicAdd(ob + 32, cC * s1);
            atomicAdd(ob + 48, cD * s1);
        }
    }
}

// ---------------------------------------------------------------------------
// Final: 2x2-mean downsample + bias + residual; both tuple outputs.
// ---------------------------------------------------------------------------
__global__ void final_kernel(const float* __restrict__ of,
                             const float* __restrict__ sff,
                             const float* __restrict__ bp,
                             float* __restrict__ dout)
{
    int tid = blockIdx.x * blockDim.x + threadIdx.x;  // 0..8191
    if (tid >= 8192) return;
    int i  = tid & 31;
    int jj = (tid >> 5) & 31;
    int bo = tid >> 10;
    int o  = bo & 3;
    const float* src = of + (size_t)bo * SQ;
    int y = jj * 2, x = i * 2;
    float dval = 0.25f * (src[y * 64 + x] + src[y * 64 + x + 1] +
                          src[(y + 1) * 64 + x] + src[(y + 1) * 64 + x + 1]) + bp[o];
    dout[tid]        = sff[tid] + dval;
    dout[8192 + tid] = dval;
}

extern "C" void kernel_launch(void* const* d_in, const int* in_sizes, int n_in,
                              void* d_out, int out_size, void* d_ws, size_t ws_size,
                              hipStream_t stream)
{
    const float* second_frame = (const float*)d_in[0];
    const float* first_frame  = (const float*)d_in[1];
    const float* sff          = (const float*)d_in[2];
    const float* ffa          = (const float*)d_in[3];
    const float* Wq = (const float*)d_in[4];
    const float* bq = (const float*)d_in[5];
    const float* Wk = (const float*)d_in[6];
    const float* bk = (const float*)d_in[7];
    const float* Wv = (const float*)d_in[8];
    const float* bv = (const float*)d_in[9];
    const float* Wp = (const float*)d_in[10];
    const float* bp = (const float*)d_in[11];
    const float* Wt = (const float*)d_in[12];
    const float* bt = (const float*)d_in[13];
    float* out = (float*)d_out;

    char* ws = (char*)d_ws;
    const size_t QKV = (size_t)2 * NHEADS * SQ * D * sizeof(unsigned short);
    unsigned short* Qb = (unsigned short*)ws;
    unsigned short* Kb = (unsigned short*)(ws + QKV);
    unsigned short* Vt = (unsigned short*)(ws + 2 * QKV);
    float* tbuf = (float*)(ws + 3 * QKV);
    float* of   = (float*)(ws + 3 * QKV + (size_t)2 * NHEADS * SQ * sizeof(float));

    prep_kernel<<<1152, 256, 0, stream>>>(second_frame, first_frame, ffa,
                                          Wq, bq, Wk, bk, Wv, bv, Wt, bt,
                                          Qb, Kb, Vt, tbuf, of);
    dim3 ag(16, 18, ZSPLIT);
    attn_kernel<<<ag, 256, 0, stream>>>(Qb, Kb, Vt, tbuf, Wp, of);
    final_kernel<<<32, 256, 0, stream>>>(of, sff, bp, out);
}

// Round 9
// 138.235 us; speedup vs baseline: 1.2037x; 1.1034x over previous
//
#include <hip/hip_runtime.h>
#include <hip/hip_bf16.h>
#include <cstddef>

#define NHEADS 9
#define D 32
#define SQ 4096
#define ZSPLIT 8
#define MBLK (SQ / ZSPLIT)     // 512 m per block
#define CHUNKS (MBLK / 64)     // 8 chunks of 64 m
#define KROW 40                // K LDS row stride (halfwords): balanced b128 banks
#define VROW 72                // V LDS row stride (halfwords): balanced b128 banks

typedef __attribute__((ext_vector_type(8))) short bf16x8;
typedef __attribute__((ext_vector_type(4))) short bf16x4;
typedef __attribute__((ext_vector_type(4))) float f32x4;

__device__ __forceinline__ unsigned int f2bf(float f) {
    unsigned int u = __float_as_uint(f);
    u += 0x7fffu + ((u >> 16) & 1u);
    return u >> 16;
}

// pack two non-negative f32 into bf16x2 by TRUNCATION: one v_perm_b32.
// result low half = bf16(lo), high half = bf16(hi).
__device__ __forceinline__ unsigned int trunc_pk(float lo, float hi) {
    return __builtin_amdgcn_perm(__float_as_uint(hi), __float_as_uint(lo),
                                 0x07060302u);
}

// relu + truncate-pack 8 scores (two QK C-tiles) into one PV B-fragment.
// ~6 VALU ops total (2x v_pk_max_f32 + 4x v_perm_b32).
__device__ __forceinline__ bf16x8 relu_pack8(f32x4 s1, f32x4 s2) {
    const f32x4 zz = {0.f, 0.f, 0.f, 0.f};
    f32x4 a = __builtin_elementwise_max(s1, zz);
    f32x4 b = __builtin_elementwise_max(s2, zz);
    union { unsigned int u[4]; bf16x8 v; } P;
    P.u[0] = trunc_pk(a[0], a[1]);
    P.u[1] = trunc_pk(a[2], a[3]);
    P.u[2] = trunc_pk(b[0], b[1]);
    P.u[3] = trunc_pk(b[2], b[3]);
    return P.v;
}

// ---------------------------------------------------------------------------
// Prep: bilinear upsample (32->64, half-pixel) + 1x1 convs -> Q,K,V (bf16) + t
// One thread per (bh, n, 8-d-group). Q/K contiguous uint4; V transposed to
// [bh][d][m] so attn stages it without a scatter. Also zeroes 'of'.
// ---------------------------------------------------------------------------
__global__ __launch_bounds__(256) void prep_kernel(
    const float* __restrict__ x2, const float* __restrict__ x1,
    const float* __restrict__ feat1,
    const float* __restrict__ Wq, const float* __restrict__ bq,
    const float* __restrict__ Wk, const float* __restrict__ bk,
    const float* __restrict__ Wv, const float* __restrict__ bv,
    const float* __restrict__ Wt, const float* __restrict__ bt,
    unsigned short* __restrict__ Qb, unsigned short* __restrict__ Kb,
    unsigned short* __restrict__ Vt, float* __restrict__ tbuf,
    float* __restrict__ of)
{
    int idx = blockIdx.x * blockDim.x + threadIdx.x;   // 0 .. 2*9*4096*4-1
    if (idx < 2 * 4 * SQ) of[idx] = 0.0f;              // zero accumulator
    int g  = idx & 3;                 // d-group: d = g*8 .. g*8+7
    int n  = (idx >> 2) & (SQ - 1);
    int bh = idx >> 14;               // 0..17
    int h  = bh % NHEADS;
    int b  = bh / NHEADS;

    float xs0 = x2[((size_t)b * 3 + 0) * SQ + n];
    float xs1 = x2[((size_t)b * 3 + 1) * SQ + n];
    float xs2 = x2[((size_t)b * 3 + 2) * SQ + n];
    float ys0 = x1[((size_t)b * 3 + 0) * SQ + n];
    float ys1 = x1[((size_t)b * 3 + 1) * SQ + n];
    float ys2 = x1[((size_t)b * 3 + 2) * SQ + n];

    // bilinear upsample coords: src = i*0.5 - 0.25 (half-pixel)
    int yy = n >> 6, xx = n & 63;
    int jy = yy >> 1, jx = xx >> 1;
    int j0, j1, i0, i1; float wy0, wy1, wx0, wx1;
    if (yy & 1) { j0 = jy; j1 = (jy < 31) ? jy + 1 : 31; wy0 = 0.75f; wy1 = 0.25f; }
    else        { j0 = (jy > 0) ? jy - 1 : 0; j1 = jy;   wy0 = 0.25f; wy1 = 0.75f; }
    if (xx & 1) { i0 = jx; i1 = (jx < 31) ? jx + 1 : 31; wx0 = 0.75f; wx1 = 0.25f; }
    else        { i0 = (jx > 0) ? jx - 1 : 0; i1 = jx;   wx0 = 0.25f; wx1 = 0.75f; }

    float fu[4];
#pragma unroll
    for (int c = 0; c < 4; ++c) {
        const float* f = feat1 + ((size_t)b * 4 + c) * 1024;
        fu[c] = wy0 * (wx0 * f[j0 * 32 + i0] + wx1 * f[j0 * 32 + i1]) +
                wy1 * (wx0 * f[j1 * 32 + i0] + wx1 * f[j1 * 32 + i1]);
    }

    const int d0 = g * 8;
    unsigned int qp[4], kp[4];
    float tpart = 0.0f;
#pragma unroll
    for (int j = 0; j < 8; ++j) {
        int d = d0 + j, hd = h * D + d;
        float q = bq[hd] + Wq[hd * 3] * xs0 + Wq[hd * 3 + 1] * xs1 + Wq[hd * 3 + 2] * xs2;
        float k = bk[hd] + Wk[hd * 3] * ys0 + Wk[hd * 3 + 1] * ys1 + Wk[hd * 3 + 2] * ys2;
        float v = bv[hd] + Wv[hd * 4] * fu[0] + Wv[hd * 4 + 1] * fu[1] +
                  Wv[hd * 4 + 2] * fu[2] + Wv[hd * 4 + 3] * fu[3];
        tpart += q * Wt[d];
        unsigned int qb_ = f2bf(q), kb_ = f2bf(k);
        if (j & 1) { qp[j >> 1] |= qb_ << 16; kp[j >> 1] |= kb_ << 16; }
        else       { qp[j >> 1]  = qb_;       kp[j >> 1]  = kb_; }
        Vt[((size_t)bh * D + d) * SQ + n] = (unsigned short)f2bf(v);
    }
    // reduce threshold partial over the 4-lane d-group
    tpart += __shfl_xor(tpart, 1);
    tpart += __shfl_xor(tpart, 2);
    if (g == 0) tbuf[(size_t)bh * SQ + n] = tpart + bt[0];

    size_t base = ((size_t)bh * SQ + n) * D + d0;
    *(uint4*)(Qb + base) = make_uint4(qp[0], qp[1], qp[2], qp[3]);
    *(uint4*)(Kb + base) = make_uint4(kp[0], kp[1], kp[2], kp[3]);
}

// ---------------------------------------------------------------------------
// Attention: block = (bh, 256 n, 512 m); wave = 64 n (4 Q-tiles).
// Grid 16x18x8 = 2304 blocks. K staged with PERMUTED rows so that
// concat(reluQK(kf1), reluQK(kf2)) is exactly the B-fragment of
// mfma_16x16x32 -> PV runs at K=32. V staged from global [d][m] with a
// straight uint4 copy. Threshold folded into the QK C-operand; relu+pack
// is 2x v_pk_max_f32 + 4x v_perm_b32 (bf16 truncation) per 8 scores.
// ---------------------------------------------------------------------------
__global__ __launch_bounds__(256, 4) void attn_kernel(
    const unsigned short* __restrict__ Qb,
    const unsigned short* __restrict__ Kb,
    const unsigned short* __restrict__ Vt,
    const float* __restrict__ tbuf,
    const float* __restrict__ Wp,
    float* __restrict__ of)
{
    __shared__ __align__(16) unsigned short Ks[64 * KROW];  // [slot][d] 5120 B
    __shared__ __align__(16) unsigned short Vs[32 * VROW];  // [d][m]    4608 B

    const int bh   = blockIdx.y;
    const int h    = bh % NHEADS;
    const int b    = bh / NHEADS;
    const int n0   = blockIdx.x * 256;
    const int mc0  = blockIdx.z * MBLK;
    const int tid  = threadIdx.x;
    const int wave = tid >> 6;
    const int lane = tid & 63;
    const int l15  = lane & 15;
    const int quad = lane >> 4;

    const int nw = n0 + wave * 64;

    // Q as B-fragment: B[d=quad*8+j][n=l15], 4 tiles at n offsets 0/16/32/48
    const unsigned short* qbase = Qb + ((size_t)bh * SQ + nw + l15) * D + quad * 8;
    bf16x8 qfA = *(const bf16x8*)(qbase);
    bf16x8 qfB = *(const bf16x8*)(qbase + 16 * D);
    bf16x8 qfC = *(const bf16x8*)(qbase + 32 * D);
    bf16x8 qfD = *(const bf16x8*)(qbase + 48 * D);

    const float SQRT32 = 5.656854249492381f;
    const float* tb = tbuf + (size_t)bh * SQ + nw + l15;
    float TA = tb[0]  * SQRT32;
    float TB = tb[16] * SQRT32;
    float TC = tb[32] * SQRT32;
    float TD = tb[48] * SQRT32;
    const f32x4 ciA = {-TA, -TA, -TA, -TA};
    const f32x4 ciB = {-TB, -TB, -TB, -TB};
    const f32x4 ciC = {-TC, -TC, -TC, -TC};
    const f32x4 ciD = {-TD, -TD, -TD, -TD};

    const uint4* Kg4 = (const uint4*)(Kb + (size_t)bh * SQ * D);
    const uint4* Vg4 = (const uint4*)(Vt + (size_t)bh * D * SQ);

    // K staging: krow = m-local 0..63 -> permuted slot; 16B per thread.
    const int krow = tid >> 2;
    const int kcol = (tid & 3) * 8;
    const int kslot = (krow & 32) + 4 * ((krow >> 3) & 3) + (krow & 3) + ((krow & 4) << 2);
    unsigned short* kdst = Ks + kslot * KROW + kcol;
    // V staging: straight copy of V[d][m-chunk]; d = tid>>3, m-col = (tid&7)*8
    const int vd = tid >> 3;
    const int vm = (tid & 7) * 8;
    unsigned short* vdst = Vs + vd * VROW + vm;
    const int vgbase = vd * (SQ / 8) + (mc0 >> 3) + (tid & 7);

    f32x4 accAl = {0.f,0.f,0.f,0.f}, accAh = {0.f,0.f,0.f,0.f};
    f32x4 accBl = {0.f,0.f,0.f,0.f}, accBh = {0.f,0.f,0.f,0.f};
    f32x4 accCl = {0.f,0.f,0.f,0.f}, accCh = {0.f,0.f,0.f,0.f};
    f32x4 accDl = {0.f,0.f,0.f,0.f}, accDh = {0.f,0.f,0.f,0.f};

    uint4 kreg = Kg4[(size_t)mc0 * 4 + tid];
    uint4 vreg = Vg4[vgbase];

    for (int c = 0; c < CHUNKS; ++c) {
        __syncthreads();   // previous compute done
        *(uint4*)kdst = kreg;
        *(uint4*)vdst = vreg;
        // prefetch next chunk (last iter over-reads into adjacent workspace)
        kreg = Kg4[(size_t)(mc0 + (c + 1) * 64) * 4 + tid];
        vreg = Vg4[vgbase + (c + 1) * 8];
        __syncthreads();   // staged data visible

#pragma unroll
        for (int g32 = 0; g32 < 2; ++g32) {
            const unsigned short* kbase = Ks + g32 * 32 * KROW;
            bf16x8 kf1 = *(const bf16x8*)(kbase + l15 * KROW + quad * 8);
            bf16x8 kf2 = *(const bf16x8*)(kbase + (16 + l15) * KROW + quad * 8);
            bf16x8 vlo = *(const bf16x8*)(Vs + l15 * VROW + g32 * 32 + quad * 8);
            bf16x8 vhi = *(const bf16x8*)(Vs + (l15 + 16) * VROW + g32 * 32 + quad * 8);

            f32x4 sA1 = __builtin_amdgcn_mfma_f32_16x16x32_bf16(kf1, qfA, ciA, 0, 0, 0);
            f32x4 sA2 = __builtin_amdgcn_mfma_f32_16x16x32_bf16(kf2, qfA, ciA, 0, 0, 0);
            f32x4 sB1 = __builtin_amdgcn_mfma_f32_16x16x32_bf16(kf1, qfB, ciB, 0, 0, 0);
            f32x4 sB2 = __builtin_amdgcn_mfma_f32_16x16x32_bf16(kf2, qfB, ciB, 0, 0, 0);
            f32x4 sC1 = __builtin_amdgcn_mfma_f32_16x16x32_bf16(kf1, qfC, ciC, 0, 0, 0);
            f32x4 sC2 = __builtin_amdgcn_mfma_f32_16x16x32_bf16(kf2, qfC, ciC, 0, 0, 0);
            f32x4 sD1 = __builtin_amdgcn_mfma_f32_16x16x32_bf16(kf1, qfD, ciD, 0, 0, 0);
            f32x4 sD2 = __builtin_amdgcn_mfma_f32_16x16x32_bf16(kf2, qfD, ciD, 0, 0, 0);

            bf16x8 pA = relu_pack8(sA1, sA2);
            bf16x8 pB = relu_pack8(sB1, sB2);
            bf16x8 pC = relu_pack8(sC1, sC2);
            bf16x8 pD = relu_pack8(sD1, sD2);

            accAl = __builtin_amdgcn_mfma_f32_16x16x32_bf16(vlo, pA, accAl, 0, 0, 0);
            accAh = __builtin_amdgcn_mfma_f32_16x16x32_bf16(vhi, pA, accAh, 0, 0, 0);
            accBl = __builtin_amdgcn_mfma_f32_16x16x32_bf16(vlo, pB, accBl, 0, 0, 0);
            accBh = __builtin_amdgcn_mfma_f32_16x16x32_bf16(vhi, pB, accBh, 0, 0, 0);
            accCl = __builtin_amdgcn_mfma_f32_16x16x32_bf16(vlo, pC, accCl, 0, 0, 0);
            accCh = __builtin_amdgcn_mfma_f32_16x16x32_bf16(vhi, pC, accCh, 0, 0, 0);
            accDl = __builtin_amdgcn_mfma_f32_16x16x32_bf16(vlo, pD, accDl, 0, 0, 0);
            accDh = __builtin_amdgcn_mfma_f32_16x16x32_bf16(vhi, pD, accDh, 0, 0, 0);
        }
    }

    // lane holds out^T[d = quad*4+r (lo) / 16+... (hi)][n] (x sqrt(32)*3000).
    // Project 288->4 with Wp, apply deferred scale, reduce quads, atomics.
    const float s1 = 5.892556509887896e-05f;   // 1/(sqrt(32)*3000)
    const float* wph = Wp + h * D + quad * 4;
#pragma unroll
    for (int o = 0; o < 4; ++o) {
        float cA = 0.f, cB = 0.f, cC = 0.f, cD = 0.f;
#pragma unroll
        for (int r = 0; r < 4; ++r) {
            float wlo = wph[o * 288 + r], whi = wph[o * 288 + 16 + r];
            cA += accAl[r] * wlo + accAh[r] * whi;
            cB += accBl[r] * wlo + accBh[r] * whi;
            cC += accCl[r] * wlo + accCh[r] * whi;
            cD += accDl[r] * wlo + accDh[r] * whi;
        }
        cA += __shfl_xor(cA, 16); cA += __shfl_xor(cA, 32);
        cB += __shfl_xor(cB, 16); cB += __shfl_xor(cB, 32);
        cC += __shfl_xor(cC, 16); cC += __shfl_xor(cC, 32);
        cD += __shfl_xor(cD, 16); cD += __shfl_xor(cD, 32);
        if (quad == 0) {
            float* ob = &of[((size_t)b * 4 + o) * SQ + nw + l15];
            atomicAdd(ob,      cA * s1);
            atomicAdd(ob + 16, cB * s1);
            atomicAdd(ob + 32, cC * s1);
            atomicAdd(ob + 48, cD * s1);
        }
    }
}

// ---------------------------------------------------------------------------
// Final: 2x2-mean downsample + bias + residual; both tuple outputs.
// ---------------------------------------------------------------------------
__global__ void final_kernel(const float* __restrict__ of,
                             const float* __restrict__ sff,
                             const float* __restrict__ bp,
                             float* __restrict__ dout)
{
    int tid = blockIdx.x * blockDim.x + threadIdx.x;  // 0..8191
    if (tid >= 8192) return;
    int i  = tid & 31;
    int jj = (tid >> 5) & 31;
    int bo = tid >> 10;
    int o  = bo & 3;
    const float* src = of + (size_t)bo * SQ;
    int y = jj * 2, x = i * 2;
    float dval = 0.25f * (src[y * 64 + x] + src[y * 64 + x + 1] +
                          src[(y + 1) * 64 + x] + src[(y + 1) * 64 + x + 1]) + bp[o];
    dout[tid]        = sff[tid] + dval;
    dout[8192 + tid] = dval;
}

extern "C" void kernel_launch(void* const* d_in, const int* in_sizes, int n_in,
                              void* d_out, int out_size, void* d_ws, size_t ws_size,
                              hipStream_t stream)
{
    const float* second_frame = (const float*)d_in[0];
    const float* first_frame  = (const float*)d_in[1];
    const float* sff          = (const float*)d_in[2];
    const float* ffa          = (const float*)d_in[3];
    const float* Wq = (const float*)d_in[4];
    const float* bq = (const float*)d_in[5];
    const float* Wk = (const float*)d_in[6];
    const float* bk = (const float*)d_in[7];
    const float* Wv = (const float*)d_in[8];
    const float* bv = (const float*)d_in[9];
    const float* Wp = (const float*)d_in[10];
    const float* bp = (const float*)d_in[11];
    const float* Wt = (const float*)d_in[12];
    const float* bt = (const float*)d_in[13];
    float* out = (float*)d_out;

    char* ws = (char*)d_ws;
    const size_t QKV = (size_t)2 * NHEADS * SQ * D * sizeof(unsigned short);
    unsigned short* Qb = (unsigned short*)ws;
    unsigned short* Kb = (unsigned short*)(ws + QKV);
    unsigned short* Vt = (unsigned short*)(ws + 2 * QKV);
    float* tbuf = (float*)(ws + 3 * QKV);
    float* of   = (float*)(ws + 3 * QKV + (size_t)2 * NHEADS * SQ * sizeof(float));

    prep_kernel<<<1152, 256, 0, stream>>>(second_frame, first_frame, ffa,
                                          Wq, bq, Wk, bk, Wv, bv, Wt, bt,
                                          Qb, Kb, Vt, tbuf, of);
    dim3 ag(16, 18, ZSPLIT);
    attn_kernel<<<ag, 256, 0, stream>>>(Qb, Kb, Vt, tbuf, Wp, of);
    final_kernel<<<32, 256, 0, stream>>>(of, sff, bp, out);
}

// Round 10
// 136.253 us; speedup vs baseline: 1.2212x; 1.0145x over previous
//
#include <hip/hip_runtime.h>
#include <hip/hip_bf16.h>
#include <cstddef>

#define NHEADS 9
#define D 32
#define SQ 4096
#define ZSPLIT 8
#define MBLK (SQ / ZSPLIT)     // 512 m per block
#define CHUNKS (MBLK / 64)     // 8 chunks of 64 m
#define KROW 40                // K LDS row stride (halfwords): uniform 2/bank on all ops
#define VROW 72                // V LDS row stride (halfwords): uniform 2/bank on all ops

typedef __attribute__((ext_vector_type(8))) short bf16x8;
typedef __attribute__((ext_vector_type(4))) short bf16x4;
typedef __attribute__((ext_vector_type(4))) float f32x4;

__device__ __forceinline__ unsigned int f2bf(float f) {
    unsigned int u = __float_as_uint(f);
    u += 0x7fffu + ((u >> 16) & 1u);
    return u >> 16;
}

// Workgroup barrier WITHOUT the vmcnt(0) drain __syncthreads() imposes.
// LDS producer/consumer ordering needs only lgkmcnt(0); global prefetch
// loads stay in flight across the barrier (their consumption is guarded by
// the compiler's register-dependency waitcnt).
__device__ __forceinline__ void lds_barrier() {
    asm volatile("s_waitcnt lgkmcnt(0)\n\ts_barrier" ::: "memory");
}

// pack two non-negative f32 into bf16x2 by TRUNCATION: one v_perm_b32.
__device__ __forceinline__ unsigned int trunc_pk(float lo, float hi) {
    return __builtin_amdgcn_perm(__float_as_uint(hi), __float_as_uint(lo),
                                 0x07060302u);
}

// relu + truncate-pack 8 scores (two QK C-tiles) into one PV B-fragment.
__device__ __forceinline__ bf16x8 relu_pack8(f32x4 s1, f32x4 s2) {
    const f32x4 zz = {0.f, 0.f, 0.f, 0.f};
    f32x4 a = __builtin_elementwise_max(s1, zz);
    f32x4 b = __builtin_elementwise_max(s2, zz);
    union { unsigned int u[4]; bf16x8 v; } P;
    P.u[0] = trunc_pk(a[0], a[1]);
    P.u[1] = trunc_pk(a[2], a[3]);
    P.u[2] = trunc_pk(b[0], b[1]);
    P.u[3] = trunc_pk(b[2], b[3]);
    return P.v;
}

// ---------------------------------------------------------------------------
// Prep: bilinear upsample (32->64, half-pixel) + 1x1 convs -> Q,K,V (bf16) + t
// One thread per (bh, n, 8-d-group). Q/K stored as contiguous uint4.
// V transposed to [bh][d][m] THROUGH LDS (stride-66 scatter = conflict-free;
// gather + coalesced 8B global stores). Also zeroes 'of'.
// ---------------------------------------------------------------------------
__global__ __launch_bounds__(256) void prep_kernel(
    const float* __restrict__ x2, const float* __restrict__ x1,
    const float* __restrict__ feat1,
    const float* __restrict__ Wq, const float* __restrict__ bq,
    const float* __restrict__ Wk, const float* __restrict__ bk,
    const float* __restrict__ Wv, const float* __restrict__ bv,
    const float* __restrict__ Wt, const float* __restrict__ bt,
    unsigned short* __restrict__ Qb, unsigned short* __restrict__ Kb,
    unsigned short* __restrict__ Vt, float* __restrict__ tbuf,
    float* __restrict__ of)
{
    __shared__ unsigned short Vls[32 * 66];   // [d][n_local], stride 66

    const int tid = threadIdx.x;
    int idx = blockIdx.x * blockDim.x + tid;   // 0 .. 2*9*4096*4-1
    if (idx < 2 * 4 * SQ) of[idx] = 0.0f;      // zero accumulator
    int g  = idx & 3;                 // d-group: d = g*8 .. g*8+7
    int nl = tid >> 2;                // n-local 0..63 (block covers 64 n, 1 bh)
    int n  = (idx >> 2) & (SQ - 1);
    int bh = idx >> 14;               // 0..17
    int h  = bh % NHEADS;
    int b  = bh / NHEADS;

    float xs0 = x2[((size_t)b * 3 + 0) * SQ + n];
    float xs1 = x2[((size_t)b * 3 + 1) * SQ + n];
    float xs2 = x2[((size_t)b * 3 + 2) * SQ + n];
    float ys0 = x1[((size_t)b * 3 + 0) * SQ + n];
    float ys1 = x1[((size_t)b * 3 + 1) * SQ + n];
    float ys2 = x1[((size_t)b * 3 + 2) * SQ + n];

    // bilinear upsample coords: src = i*0.5 - 0.25 (half-pixel)
    int yy = n >> 6, xx = n & 63;
    int jy = yy >> 1, jx = xx >> 1;
    int j0, j1, i0, i1; float wy0, wy1, wx0, wx1;
    if (yy & 1) { j0 = jy; j1 = (jy < 31) ? jy + 1 : 31; wy0 = 0.75f; wy1 = 0.25f; }
    else        { j0 = (jy > 0) ? jy - 1 : 0; j1 = jy;   wy0 = 0.25f; wy1 = 0.75f; }
    if (xx & 1) { i0 = jx; i1 = (jx < 31) ? jx + 1 : 31; wx0 = 0.75f; wx1 = 0.25f; }
    else        { i0 = (jx > 0) ? jx - 1 : 0; i1 = jx;   wx0 = 0.25f; wx1 = 0.75f; }

    float fu[4];
#pragma unroll
    for (int c = 0; c < 4; ++c) {
        const float* f = feat1 + ((size_t)b * 4 + c) * 1024;
        fu[c] = wy0 * (wx0 * f[j0 * 32 + i0] + wx1 * f[j0 * 32 + i1]) +
                wy1 * (wx0 * f[j1 * 32 + i0] + wx1 * f[j1 * 32 + i1]);
    }

    const int d0 = g * 8;
    unsigned int qp[4], kp[4];
    float tpart = 0.0f;
#pragma unroll
    for (int j = 0; j < 8; ++j) {
        int d = d0 + j, hd = h * D + d;
        float q = bq[hd] + Wq[hd * 3] * xs0 + Wq[hd * 3 + 1] * xs1 + Wq[hd * 3 + 2] * xs2;
        float k = bk[hd] + Wk[hd * 3] * ys0 + Wk[hd * 3 + 1] * ys1 + Wk[hd * 3 + 2] * ys2;
        float v = bv[hd] + Wv[hd * 4] * fu[0] + Wv[hd * 4 + 1] * fu[1] +
                  Wv[hd * 4 + 2] * fu[2] + Wv[hd * 4 + 3] * fu[3];
        tpart += q * Wt[d];
        unsigned int qb_ = f2bf(q), kb_ = f2bf(k);
        if (j & 1) { qp[j >> 1] |= qb_ << 16; kp[j >> 1] |= kb_ << 16; }
        else       { qp[j >> 1]  = qb_;       kp[j >> 1]  = kb_; }
        Vls[d * 66 + nl] = (unsigned short)f2bf(v);   // conflict-free scatter
    }
    // reduce threshold partial over the 4-lane d-group
    tpart += __shfl_xor(tpart, 1);
    tpart += __shfl_xor(tpart, 2);
    if (g == 0) tbuf[(size_t)bh * SQ + n] = tpart + bt[0];

    size_t base = ((size_t)bh * SQ + n) * D + d0;
    *(uint4*)(Qb + base) = make_uint4(qp[0], qp[1], qp[2], qp[3]);
    *(uint4*)(Kb + base) = make_uint4(kp[0], kp[1], kp[2], kp[3]);

    __syncthreads();
    // coalesced V write-out: thread -> row r = tid>>3, 4-u16 chunk c4 = tid&7
    {
        int r  = tid >> 3;
        int c4 = tid & 7;
        int n0 = (blockIdx.x & 63) * 64;
        unsigned int w0 = *(const unsigned int*)&Vls[r * 66 + c4 * 4];
        unsigned int w1 = *(const unsigned int*)&Vls[r * 66 + c4 * 4 + 2];
        *(uint2*)(Vt + ((size_t)bh * D + r) * SQ + n0 + c4 * 4) = make_uint2(w0, w1);
    }
}

// ---------------------------------------------------------------------------
// Attention: block = (bh, 256 n, 512 m); wave = 64 n (4 Q-tiles).
// Grid 16x18x8 = 2304 blocks. DOUBLE-BUFFERED LDS with raw lgkmcnt barriers
// (one per chunk, no vmcnt drain -> global prefetch truly overlaps compute).
// K staged with PERMUTED rows so concat(reluQK(kf1), reluQK(kf2)) is exactly
// the B-fragment of mfma_16x16x32 -> PV at K=32. Threshold folded into the
// QK C-operand; relu+pack = v_max + v_perm truncation.
// ---------------------------------------------------------------------------
#define COMPUTE(KS, VS)                                                          \
    {                                                                            \
        _Pragma("unroll")                                                        \
        for (int g32 = 0; g32 < 2; ++g32) {                                      \
            const unsigned short* kbase = KS + g32 * 32 * KROW;                  \
            bf16x8 kf1 = *(const bf16x8*)(kbase + l15 * KROW + quad * 8);        \
            bf16x8 kf2 = *(const bf16x8*)(kbase + (16 + l15) * KROW + quad * 8); \
            bf16x8 vlo = *(const bf16x8*)(VS + l15 * VROW + g32 * 32 + quad * 8);\
            bf16x8 vhi = *(const bf16x8*)(VS + (l15 + 16) * VROW + g32 * 32 + quad * 8);\
            f32x4 sA1 = __builtin_amdgcn_mfma_f32_16x16x32_bf16(kf1, qfA, ciA, 0, 0, 0);\
            f32x4 sA2 = __builtin_amdgcn_mfma_f32_16x16x32_bf16(kf2, qfA, ciA, 0, 0, 0);\
            f32x4 sB1 = __builtin_amdgcn_mfma_f32_16x16x32_bf16(kf1, qfB, ciB, 0, 0, 0);\
            f32x4 sB2 = __builtin_amdgcn_mfma_f32_16x16x32_bf16(kf2, qfB, ciB, 0, 0, 0);\
            f32x4 sC1 = __builtin_amdgcn_mfma_f32_16x16x32_bf16(kf1, qfC, ciC, 0, 0, 0);\
            f32x4 sC2 = __builtin_amdgcn_mfma_f32_16x16x32_bf16(kf2, qfC, ciC, 0, 0, 0);\
            f32x4 sD1 = __builtin_amdgcn_mfma_f32_16x16x32_bf16(kf1, qfD, ciD, 0, 0, 0);\
            f32x4 sD2 = __builtin_amdgcn_mfma_f32_16x16x32_bf16(kf2, qfD, ciD, 0, 0, 0);\
            bf16x8 pA = relu_pack8(sA1, sA2);                                    \
            bf16x8 pB = relu_pack8(sB1, sB2);                                    \
            bf16x8 pC = relu_pack8(sC1, sC2);                                    \
            bf16x8 pD = relu_pack8(sD1, sD2);                                    \
            accAl = __builtin_amdgcn_mfma_f32_16x16x32_bf16(vlo, pA, accAl, 0, 0, 0);\
            accAh = __builtin_amdgcn_mfma_f32_16x16x32_bf16(vhi, pA, accAh, 0, 0, 0);\
            accBl = __builtin_amdgcn_mfma_f32_16x16x32_bf16(vlo, pB, accBl, 0, 0, 0);\
            accBh = __builtin_amdgcn_mfma_f32_16x16x32_bf16(vhi, pB, accBh, 0, 0, 0);\
            accCl = __builtin_amdgcn_mfma_f32_16x16x32_bf16(vlo, pC, accCl, 0, 0, 0);\
            accCh = __builtin_amdgcn_mfma_f32_16x16x32_bf16(vhi, pC, accCh, 0, 0, 0);\
            accDl = __builtin_amdgcn_mfma_f32_16x16x32_bf16(vlo, pD, accDl, 0, 0, 0);\
            accDh = __builtin_amdgcn_mfma_f32_16x16x32_bf16(vhi, pD, accDh, 0, 0, 0);\
        }                                                                        \
    }

__global__ __launch_bounds__(256, 4) void attn_kernel(
    const unsigned short* __restrict__ Qb,
    const unsigned short* __restrict__ Kb,
    const unsigned short* __restrict__ Vt,
    const float* __restrict__ tbuf,
    const float* __restrict__ Wp,
    float* __restrict__ of)
{
    __shared__ __align__(16) unsigned short Ks0[64 * KROW];
    __shared__ __align__(16) unsigned short Ks1[64 * KROW];
    __shared__ __align__(16) unsigned short Vs0[32 * VROW];
    __shared__ __align__(16) unsigned short Vs1[32 * VROW];

    const int bh   = blockIdx.y;
    const int h    = bh % NHEADS;
    const int b    = bh / NHEADS;
    const int n0   = blockIdx.x * 256;
    const int mc0  = blockIdx.z * MBLK;
    const int tid  = threadIdx.x;
    const int wave = tid >> 6;
    const int lane = tid & 63;
    const int l15  = lane & 15;
    const int quad = lane >> 4;

    const int nw = n0 + wave * 64;

    // Q as B-fragment: B[d=quad*8+j][n=l15], 4 tiles at n offsets 0/16/32/48
    const unsigned short* qbase = Qb + ((size_t)bh * SQ + nw + l15) * D + quad * 8;
    bf16x8 qfA = *(const bf16x8*)(qbase);
    bf16x8 qfB = *(const bf16x8*)(qbase + 16 * D);
    bf16x8 qfC = *(const bf16x8*)(qbase + 32 * D);
    bf16x8 qfD = *(const bf16x8*)(qbase + 48 * D);

    const float SQRT32 = 5.656854249492381f;
    const float* tb = tbuf + (size_t)bh * SQ + nw + l15;
    float TA = tb[0]  * SQRT32;
    float TB = tb[16] * SQRT32;
    float TC = tb[32] * SQRT32;
    float TD = tb[48] * SQRT32;
    const f32x4 ciA = {-TA, -TA, -TA, -TA};
    const f32x4 ciB = {-TB, -TB, -TB, -TB};
    const f32x4 ciC = {-TC, -TC, -TC, -TC};
    const f32x4 ciD = {-TD, -TD, -TD, -TD};

    const uint4* Kg4 = (const uint4*)(Kb + (size_t)bh * SQ * D);
    const uint4* Vg4 = (const uint4*)(Vt + (size_t)bh * D * SQ);

    // K staging: krow = m-local 0..63 -> permuted slot; 16B per thread.
    const int krow = tid >> 2;
    const int kcol = (tid & 3) * 8;
    const int kslot = (krow & 32) + 4 * ((krow >> 3) & 3) + (krow & 3) + ((krow & 4) << 2);
    unsigned short* kdst0 = Ks0 + kslot * KROW + kcol;
    unsigned short* kdst1 = Ks1 + kslot * KROW + kcol;
    // V staging: straight copy of V[d][m-chunk]; d = tid>>3, m-col = (tid&7)*8
    const int vd = tid >> 3;
    const int vm = (tid & 7) * 8;
    unsigned short* vdst0 = Vs0 + vd * VROW + vm;
    unsigned short* vdst1 = Vs1 + vd * VROW + vm;
    const int vgbase = vd * (SQ / 8) + (mc0 >> 3) + (tid & 7);

    f32x4 accAl = {0.f,0.f,0.f,0.f}, accAh = {0.f,0.f,0.f,0.f};
    f32x4 accBl = {0.f,0.f,0.f,0.f}, accBh = {0.f,0.f,0.f,0.f};
    f32x4 accCl = {0.f,0.f,0.f,0.f}, accCh = {0.f,0.f,0.f,0.f};
    f32x4 accDl = {0.f,0.f,0.f,0.f}, accDh = {0.f,0.f,0.f,0.f};

    // prologue: chunk0 -> buf0; issue chunk1 loads
    uint4 k0 = Kg4[(size_t)mc0 * 4 + tid];
    uint4 v0 = Vg4[vgbase];
    *(uint4*)kdst0 = k0;
    *(uint4*)vdst0 = v0;
    uint4 k1 = Kg4[(size_t)(mc0 + 64) * 4 + tid];
    uint4 v1 = Vg4[vgbase + 8];
    lds_barrier();

    for (int c = 0; c < CHUNKS; c += 2) {
        // even iter: compute buf0 (chunk c); write buf1 <- chunk c+1; load chunk c+2
        *(uint4*)kdst1 = k1;
        *(uint4*)vdst1 = v1;
        k0 = Kg4[(size_t)(mc0 + (c + 2) * 64) * 4 + tid];
        v0 = Vg4[vgbase + (c + 2) * 8];
        COMPUTE(Ks0, Vs0);
        lds_barrier();
        // odd iter: compute buf1 (chunk c+1); write buf0 <- chunk c+2; load chunk c+3
        *(uint4*)kdst0 = k0;
        *(uint4*)vdst0 = v0;
        k1 = Kg4[(size_t)(mc0 + (c + 3) * 64) * 4 + tid];
        v1 = Vg4[vgbase + (c + 3) * 8];
        COMPUTE(Ks1, Vs1);
        lds_barrier();
    }

    // lane holds out^T[d = quad*4+r (lo) / 16+... (hi)][n] (x sqrt(32)*3000).
    // Project 288->4 with Wp, apply deferred scale, reduce quads, atomics.
    const float s1 = 5.892556509887896e-05f;   // 1/(sqrt(32)*3000)
    const float* wph = Wp + h * D + quad * 4;
#pragma unroll
    for (int o = 0; o < 4; ++o) {
        float cA = 0.f, cB = 0.f, cC = 0.f, cD = 0.f;
#pragma unroll
        for (int r = 0; r < 4; ++r) {
            float wlo = wph[o * 288 + r], whi = wph[o * 288 + 16 + r];
            cA += accAl[r] * wlo + accAh[r] * whi;
            cB += accBl[r] * wlo + accBh[r] * whi;
            cC += accCl[r] * wlo + accCh[r] * whi;
            cD += accDl[r] * wlo + accDh[r] * whi;
        }
        cA += __shfl_xor(cA, 16); cA += __shfl_xor(cA, 32);
        cB += __shfl_xor(cB, 16); cB += __shfl_xor(cB, 32);
        cC += __shfl_xor(cC, 16); cC += __shfl_xor(cC, 32);
        cD += __shfl_xor(cD, 16); cD += __shfl_xor(cD, 32);
        if (quad == 0) {
            float* ob = &of[((size_t)b * 4 + o) * SQ + nw + l15];
            atomicAdd(ob,      cA * s1);
            atomicAdd(ob + 16, cB * s1);
            atomicAdd(ob + 32, cC * s1);
            atomicAdd(ob + 48, cD * s1);
        }
    }
}

// ---------------------------------------------------------------------------
// Final: 2x2-mean downsample + bias + residual; both tuple outputs.
// ---------------------------------------------------------------------------
__global__ void final_kernel(const float* __restrict__ of,
                             const float* __restrict__ sff,
                             const float* __restrict__ bp,
                             float* __restrict__ dout)
{
    int tid = blockIdx.x * blockDim.x + threadIdx.x;  // 0..8191
    if (tid >= 8192) return;
    int i  = tid & 31;
    int jj = (tid >> 5) & 31;
    int bo = tid >> 10;
    int o  = bo & 3;
    const float* src = of + (size_t)bo * SQ;
    int y = jj * 2, x = i * 2;
    float dval = 0.25f * (src[y * 64 + x] + src[y * 64 + x + 1] +
                          src[(y + 1) * 64 + x] + src[(y + 1) * 64 + x + 1]) + bp[o];
    dout[tid]        = sff[tid] + dval;
    dout[8192 + tid] = dval;
}

extern "C" void kernel_launch(void* const* d_in, const int* in_sizes, int n_in,
                              void* d_out, int out_size, void* d_ws, size_t ws_size,
                              hipStream_t stream)
{
    const float* second_frame = (const float*)d_in[0];
    const float* first_frame  = (const float*)d_in[1];
    const float* sff          = (const float*)d_in[2];
    const float* ffa          = (const float*)d_in[3];
    const float* Wq = (const float*)d_in[4];
    const float* bq = (const float*)d_in[5];
    const float* Wk = (const float*)d_in[6];
    const float* bk = (const float*)d_in[7];
    const float* Wv = (const float*)d_in[8];
    const float* bv = (const float*)d_in[9];
    const float* Wp = (const float*)d_in[10];
    const float* bp = (const float*)d_in[11];
    const float* Wt = (const float*)d_in[12];
    const float* bt = (const float*)d_in[13];
    float* out = (float*)d_out;

    char* ws = (char*)d_ws;
    const size_t QKV = (size_t)2 * NHEADS * SQ * D * sizeof(unsigned short);
    unsigned short* Qb = (unsigned short*)ws;
    unsigned short* Kb = (unsigned short*)(ws + QKV);
    unsigned short* Vt = (unsigned short*)(ws + 2 * QKV);
    float* tbuf = (float*)(ws + 3 * QKV);
    float* of   = (float*)(ws + 3 * QKV + (size_t)2 * NHEADS * SQ * sizeof(float));

    prep_kernel<<<1152, 256, 0, stream>>>(second_frame, first_frame, ffa,
                                          Wq, bq, Wk, bk, Wv, bv, Wt, bt,
                                          Qb, Kb, Vt, tbuf, of);
    dim3 ag(16, 18, ZSPLIT);
    attn_kernel<<<ag, 256, 0, stream>>>(Qb, Kb, Vt, tbuf, Wp, of);
    final_kernel<<<32, 256, 0, stream>>>(of, sff, bp, out);
}

// Round 11
// 133.311 us; speedup vs baseline: 1.2482x; 1.0221x over previous
//
#include <hip/hip_runtime.h>
#include <hip/hip_bf16.h>
#include <cstddef>

#define NHEADS 9
#define D 32
#define SQ 4096
#define ZSPLIT 8
#define MBLK (SQ / ZSPLIT)     // 512 m per block
#define CHUNKS (MBLK / 64)     // 8 chunks of 64 m
#define KROW 40                // K LDS row stride (halfwords)
#define VROW 72                // V LDS row stride (halfwords)

typedef __attribute__((ext_vector_type(8))) short bf16x8;
typedef __attribute__((ext_vector_type(4))) short bf16x4;
typedef __attribute__((ext_vector_type(4))) float f32x4;

__device__ __forceinline__ unsigned int f2bf(float f) {
    unsigned int u = __float_as_uint(f);
    u += 0x7fffu + ((u >> 16) & 1u);
    return u >> 16;
}

// Workgroup barrier WITHOUT the vmcnt(0) drain __syncthreads() imposes.
// LDS producer/consumer ordering needs only lgkmcnt(0); global prefetch
// loads stay in flight across the barrier.
__device__ __forceinline__ void lds_barrier() {
    asm volatile("s_waitcnt lgkmcnt(0)\n\ts_barrier" ::: "memory");
}

// pack two non-negative f32 into bf16x2 by TRUNCATION: one v_perm_b32.
__device__ __forceinline__ unsigned int trunc_pk(float lo, float hi) {
    return __builtin_amdgcn_perm(__float_as_uint(hi), __float_as_uint(lo),
                                 0x07060302u);
}

// relu + truncate-pack 8 scores (two QK C-tiles) into one PV B-fragment.
__device__ __forceinline__ bf16x8 relu_pack8(f32x4 s1, f32x4 s2) {
    const f32x4 zz = {0.f, 0.f, 0.f, 0.f};
    f32x4 a = __builtin_elementwise_max(s1, zz);
    f32x4 b = __builtin_elementwise_max(s2, zz);
    union { unsigned int u[4]; bf16x8 v; } P;
    P.u[0] = trunc_pk(a[0], a[1]);
    P.u[1] = trunc_pk(a[2], a[3]);
    P.u[2] = trunc_pk(b[0], b[1]);
    P.u[3] = trunc_pk(b[2], b[3]);
    return P.v;
}

// ---------------------------------------------------------------------------
// Prep: bilinear upsample (32->64, half-pixel) + 1x1 convs -> Q,K,V (bf16) + t
// One thread per (bh, n, 8-d-group). Q/K stored as contiguous uint4.
// V transposed to [bh][d][m] THROUGH LDS (stride-66 scatter = conflict-free;
// gather + coalesced 8B global stores). Also zeroes 'of'.
// ---------------------------------------------------------------------------
__global__ __launch_bounds__(256) void prep_kernel(
    const float* __restrict__ x2, const float* __restrict__ x1,
    const float* __restrict__ feat1,
    const float* __restrict__ Wq, const float* __restrict__ bq,
    const float* __restrict__ Wk, const float* __restrict__ bk,
    const float* __restrict__ Wv, const float* __restrict__ bv,
    const float* __restrict__ Wt, const float* __restrict__ bt,
    unsigned short* __restrict__ Qb, unsigned short* __restrict__ Kb,
    unsigned short* __restrict__ Vt, float* __restrict__ tbuf,
    float* __restrict__ of)
{
    __shared__ unsigned short Vls[32 * 66];   // [d][n_local], stride 66

    const int tid = threadIdx.x;
    int idx = blockIdx.x * blockDim.x + tid;   // 0 .. 2*9*4096*4-1
    if (idx < 2 * 4 * SQ) of[idx] = 0.0f;      // zero accumulator
    int g  = idx & 3;                 // d-group: d = g*8 .. g*8+7
    int nl = tid >> 2;                // n-local 0..63 (block covers 64 n, 1 bh)
    int n  = (idx >> 2) & (SQ - 1);
    int bh = idx >> 14;               // 0..17
    int h  = bh % NHEADS;
    int b  = bh / NHEADS;

    float xs0 = x2[((size_t)b * 3 + 0) * SQ + n];
    float xs1 = x2[((size_t)b * 3 + 1) * SQ + n];
    float xs2 = x2[((size_t)b * 3 + 2) * SQ + n];
    float ys0 = x1[((size_t)b * 3 + 0) * SQ + n];
    float ys1 = x1[((size_t)b * 3 + 1) * SQ + n];
    float ys2 = x1[((size_t)b * 3 + 2) * SQ + n];

    // bilinear upsample coords: src = i*0.5 - 0.25 (half-pixel)
    int yy = n >> 6, xx = n & 63;
    int jy = yy >> 1, jx = xx >> 1;
    int j0, j1, i0, i1; float wy0, wy1, wx0, wx1;
    if (yy & 1) { j0 = jy; j1 = (jy < 31) ? jy + 1 : 31; wy0 = 0.75f; wy1 = 0.25f; }
    else        { j0 = (jy > 0) ? jy - 1 : 0; j1 = jy;   wy0 = 0.25f; wy1 = 0.75f; }
    if (xx & 1) { i0 = jx; i1 = (jx < 31) ? jx + 1 : 31; wx0 = 0.75f; wx1 = 0.25f; }
    else        { i0 = (jx > 0) ? jx - 1 : 0; i1 = jx;   wx0 = 0.25f; wx1 = 0.75f; }

    float fu[4];
#pragma unroll
    for (int c = 0; c < 4; ++c) {
        const float* f = feat1 + ((size_t)b * 4 + c) * 1024;
        fu[c] = wy0 * (wx0 * f[j0 * 32 + i0] + wx1 * f[j0 * 32 + i1]) +
                wy1 * (wx0 * f[j1 * 32 + i0] + wx1 * f[j1 * 32 + i1]);
    }

    const int d0 = g * 8;
    unsigned int qp[4], kp[4];
    float tpart = 0.0f;
#pragma unroll
    for (int j = 0; j < 8; ++j) {
        int d = d0 + j, hd = h * D + d;
        float q = bq[hd] + Wq[hd * 3] * xs0 + Wq[hd * 3 + 1] * xs1 + Wq[hd * 3 + 2] * xs2;
        float k = bk[hd] + Wk[hd * 3] * ys0 + Wk[hd * 3 + 1] * ys1 + Wk[hd * 3 + 2] * ys2;
        float v = bv[hd] + Wv[hd * 4] * fu[0] + Wv[hd * 4 + 1] * fu[1] +
                  Wv[hd * 4 + 2] * fu[2] + Wv[hd * 4 + 3] * fu[3];
        tpart += q * Wt[d];
        unsigned int qb_ = f2bf(q), kb_ = f2bf(k);
        if (j & 1) { qp[j >> 1] |= qb_ << 16; kp[j >> 1] |= kb_ << 16; }
        else       { qp[j >> 1]  = qb_;       kp[j >> 1]  = kb_; }
        Vls[d * 66 + nl] = (unsigned short)f2bf(v);   // conflict-free scatter
    }
    // reduce threshold partial over the 4-lane d-group
    tpart += __shfl_xor(tpart, 1);
    tpart += __shfl_xor(tpart, 2);
    if (g == 0) tbuf[(size_t)bh * SQ + n] = tpart + bt[0];

    size_t base = ((size_t)bh * SQ + n) * D + d0;
    *(uint4*)(Qb + base) = make_uint4(qp[0], qp[1], qp[2], qp[3]);
    *(uint4*)(Kb + base) = make_uint4(kp[0], kp[1], kp[2], kp[3]);

    __syncthreads();
    // coalesced V write-out: thread -> row r = tid>>3, 4-u16 chunk c4 = tid&7
    {
        int r  = tid >> 3;
        int c4 = tid & 7;
        int n0 = (blockIdx.x & 63) * 64;
        unsigned int w0 = *(const unsigned int*)&Vls[r * 66 + c4 * 4];
        unsigned int w1 = *(const unsigned int*)&Vls[r * 66 + c4 * 4 + 2];
        *(uint2*)(Vt + ((size_t)bh * D + r) * SQ + n0 + c4 * 4) = make_uint2(w0, w1);
    }
}

// ---------------------------------------------------------------------------
// Attention: block = (bh, 256 n, 512 m); wave = 64 n (4 Q-tiles).
// Grid 16x18x8 = 2304 blocks. Double-buffered LDS, ONE lgkm-only barrier
// per chunk, single prefetch register set (8 VGPRs live across compute):
//   COMPUTE(buf[c&1]); ds_write buf[~c&1] <- (kn,vn)  [vmcnt wait covers
//   data loaded a full COMPUTE ago]; reload kn,vn 2 chunks ahead (guarded);
//   barrier. No vmcnt(0) drain anywhere in the loop; no OOB prefetch.
// K staged with PERMUTED rows so concat(reluQK(kf1), reluQK(kf2)) is exactly
// the B-fragment of mfma_16x16x32 -> PV at K=32. Threshold folded into the
// QK C-operand; relu+pack = v_max + v_perm truncation.
// ---------------------------------------------------------------------------
#define COMPUTE(KS, VS)                                                          \
    {                                                                            \
        _Pragma("unroll")                                                        \
        for (int g32 = 0; g32 < 2; ++g32) {                                      \
            const unsigned short* kbase = KS + g32 * 32 * KROW;                  \
            bf16x8 kf1 = *(const bf16x8*)(kbase + l15 * KROW + quad * 8);        \
            bf16x8 kf2 = *(const bf16x8*)(kbase + (16 + l15) * KROW + quad * 8); \
            bf16x8 vlo = *(const bf16x8*)(VS + l15 * VROW + g32 * 32 + quad * 8);\
            bf16x8 vhi = *(const bf16x8*)(VS + (l15 + 16) * VROW + g32 * 32 + quad * 8);\
            f32x4 sA1 = __builtin_amdgcn_mfma_f32_16x16x32_bf16(kf1, qfA, ciA, 0, 0, 0);\
            f32x4 sA2 = __builtin_amdgcn_mfma_f32_16x16x32_bf16(kf2, qfA, ciA, 0, 0, 0);\
            f32x4 sB1 = __builtin_amdgcn_mfma_f32_16x16x32_bf16(kf1, qfB, ciB, 0, 0, 0);\
            f32x4 sB2 = __builtin_amdgcn_mfma_f32_16x16x32_bf16(kf2, qfB, ciB, 0, 0, 0);\
            f32x4 sC1 = __builtin_amdgcn_mfma_f32_16x16x32_bf16(kf1, qfC, ciC, 0, 0, 0);\
            f32x4 sC2 = __builtin_amdgcn_mfma_f32_16x16x32_bf16(kf2, qfC, ciC, 0, 0, 0);\
            f32x4 sD1 = __builtin_amdgcn_mfma_f32_16x16x32_bf16(kf1, qfD, ciD, 0, 0, 0);\
            f32x4 sD2 = __builtin_amdgcn_mfma_f32_16x16x32_bf16(kf2, qfD, ciD, 0, 0, 0);\
            bf16x8 pA = relu_pack8(sA1, sA2);                                    \
            bf16x8 pB = relu_pack8(sB1, sB2);                                    \
            bf16x8 pC = relu_pack8(sC1, sC2);                                    \
            bf16x8 pD = relu_pack8(sD1, sD2);                                    \
            accAl = __builtin_amdgcn_mfma_f32_16x16x32_bf16(vlo, pA, accAl, 0, 0, 0);\
            accAh = __builtin_amdgcn_mfma_f32_16x16x32_bf16(vhi, pA, accAh, 0, 0, 0);\
            accBl = __builtin_amdgcn_mfma_f32_16x16x32_bf16(vlo, pB, accBl, 0, 0, 0);\
            accBh = __builtin_amdgcn_mfma_f32_16x16x32_bf16(vhi, pB, accBh, 0, 0, 0);\
            accCl = __builtin_amdgcn_mfma_f32_16x16x32_bf16(vlo, pC, accCl, 0, 0, 0);\
            accCh = __builtin_amdgcn_mfma_f32_16x16x32_bf16(vhi, pC, accCh, 0, 0, 0);\
            accDl = __builtin_amdgcn_mfma_f32_16x16x32_bf16(vlo, pD, accDl, 0, 0, 0);\
            accDh = __builtin_amdgcn_mfma_f32_16x16x32_bf16(vhi, pD, accDh, 0, 0, 0);\
        }                                                                        \
    }

__global__ __launch_bounds__(256, 4) void attn_kernel(
    const unsigned short* __restrict__ Qb,
    const unsigned short* __restrict__ Kb,
    const unsigned short* __restrict__ Vt,
    const float* __restrict__ tbuf,
    const float* __restrict__ Wp,
    float* __restrict__ of)
{
    __shared__ __align__(16) unsigned short Ks0[64 * KROW];
    __shared__ __align__(16) unsigned short Ks1[64 * KROW];
    __shared__ __align__(16) unsigned short Vs0[32 * VROW];
    __shared__ __align__(16) unsigned short Vs1[32 * VROW];

    const int bh   = blockIdx.y;
    const int h    = bh % NHEADS;
    const int b    = bh / NHEADS;
    const int n0   = blockIdx.x * 256;
    const int mc0  = blockIdx.z * MBLK;
    const int tid  = threadIdx.x;
    const int wave = tid >> 6;
    const int lane = tid & 63;
    const int l15  = lane & 15;
    const int quad = lane >> 4;

    const int nw = n0 + wave * 64;

    // Q as B-fragment: B[d=quad*8+j][n=l15], 4 tiles at n offsets 0/16/32/48
    const unsigned short* qbase = Qb + ((size_t)bh * SQ + nw + l15) * D + quad * 8;
    bf16x8 qfA = *(const bf16x8*)(qbase);
    bf16x8 qfB = *(const bf16x8*)(qbase + 16 * D);
    bf16x8 qfC = *(const bf16x8*)(qbase + 32 * D);
    bf16x8 qfD = *(const bf16x8*)(qbase + 48 * D);

    const float SQRT32 = 5.656854249492381f;
    const float* tb = tbuf + (size_t)bh * SQ + nw + l15;
    float TA = tb[0]  * SQRT32;
    float TB = tb[16] * SQRT32;
    float TC = tb[32] * SQRT32;
    float TD = tb[48] * SQRT32;
    const f32x4 ciA = {-TA, -TA, -TA, -TA};
    const f32x4 ciB = {-TB, -TB, -TB, -TB};
    const f32x4 ciC = {-TC, -TC, -TC, -TC};
    const f32x4 ciD = {-TD, -TD, -TD, -TD};

    const uint4* Kg4 = (const uint4*)(Kb + (size_t)bh * SQ * D);
    const uint4* Vg4 = (const uint4*)(Vt + (size_t)bh * D * SQ);

    // K staging: krow = m-local 0..63 -> permuted slot; 16B per thread.
    const int krow = tid >> 2;
    const int kcol = (tid & 3) * 8;
    const int kslot = (krow & 32) + 4 * ((krow >> 3) & 3) + (krow & 3) + ((krow & 4) << 2);
    unsigned short* kdst0 = Ks0 + kslot * KROW + kcol;
    unsigned short* kdst1 = Ks1 + kslot * KROW + kcol;
    // V staging: straight copy of V[d][m-chunk]; d = tid>>3, m-col = (tid&7)*8
    const int vd = tid >> 3;
    const int vm = (tid & 7) * 8;
    unsigned short* vdst0 = Vs0 + vd * VROW + vm;
    unsigned short* vdst1 = Vs1 + vd * VROW + vm;
    const int vgbase = vd * (SQ / 8) + (mc0 >> 3) + (tid & 7);

    f32x4 accAl = {0.f,0.f,0.f,0.f}, accAh = {0.f,0.f,0.f,0.f};
    f32x4 accBl = {0.f,0.f,0.f,0.f}, accBh = {0.f,0.f,0.f,0.f};
    f32x4 accCl = {0.f,0.f,0.f,0.f}, accCh = {0.f,0.f,0.f,0.f};
    f32x4 accDl = {0.f,0.f,0.f,0.f}, accDh = {0.f,0.f,0.f,0.f};

    // prologue: stage chunk0 -> buf0; leave chunk1 in flight in (kn,vn)
    {
        uint4 k0 = Kg4[(size_t)mc0 * 4 + tid];
        uint4 v0 = Vg4[vgbase];
        *(uint4*)kdst0 = k0;
        *(uint4*)vdst0 = v0;
    }
    uint4 kn = Kg4[(size_t)(mc0 + 64) * 4 + tid];
    uint4 vn = Vg4[vgbase + 8];
    lds_barrier();

#pragma unroll
    for (int c = 0; c < CHUNKS; c += 2) {
        // compute chunk c from buf0; stage chunk c+1 -> buf1 (vmcnt wait
        // covers loads issued a full COMPUTE ago); reload 2 ahead (guarded)
        COMPUTE(Ks0, Vs0);
        *(uint4*)kdst1 = kn;
        *(uint4*)vdst1 = vn;
        if (c + 2 < CHUNKS) {
            kn = Kg4[(size_t)(mc0 + (c + 2) * 64) * 4 + tid];
            vn = Vg4[vgbase + (c + 2) * 8];
        }
        lds_barrier();

        // compute chunk c+1 from buf1; stage chunk c+2 -> buf0 (guarded)
        COMPUTE(Ks1, Vs1);
        if (c + 2 < CHUNKS) {
            *(uint4*)kdst0 = kn;
            *(uint4*)vdst0 = vn;
            kn = Kg4[(size_t)(mc0 + (c + 3) * 64) * 4 + tid];
            vn = Vg4[vgbase + (c + 3) * 8];
            lds_barrier();
        }
    }

    // lane holds out^T[d = quad*4+r (lo) / 16+... (hi)][n] (x sqrt(32)*3000).
    // Project 288->4 with Wp, apply deferred scale, reduce quads, atomics.
    const float s1 = 5.892556509887896e-05f;   // 1/(sqrt(32)*3000)
    const float* wph = Wp + h * D + quad * 4;
#pragma unroll
    for (int o = 0; o < 4; ++o) {
        float cA = 0.f, cB = 0.f, cC = 0.f, cD = 0.f;
#pragma unroll
        for (int r = 0; r < 4; ++r) {
            float wlo = wph[o * 288 + r], whi = wph[o * 288 + 16 + r];
            cA += accAl[r] * wlo + accAh[r] * whi;
            cB += accBl[r] * wlo + accBh[r] * whi;
            cC += accCl[r] * wlo + accCh[r] * whi;
            cD += accDl[r] * wlo + accDh[r] * whi;
        }
        cA += __shfl_xor(cA, 16); cA += __shfl_xor(cA, 32);
        cB += __shfl_xor(cB, 16); cB += __shfl_xor(cB, 32);
        cC += __shfl_xor(cC, 16); cC += __shfl_xor(cC, 32);
        cD += __shfl_xor(cD, 16); cD += __shfl_xor(cD, 32);
        if (quad == 0) {
            float* ob = &of[((size_t)b * 4 + o) * SQ + nw + l15];
            atomicAdd(ob,      cA * s1);
            atomicAdd(ob + 16, cB * s1);
            atomicAdd(ob + 32, cC * s1);
            atomicAdd(ob + 48, cD * s1);
        }
    }
}

// ---------------------------------------------------------------------------
// Final: 2x2-mean downsample + bias + residual; both tuple outputs.
// ---------------------------------------------------------------------------
__global__ void final_kernel(const float* __restrict__ of,
                             const float* __restrict__ sff,
                             const float* __restrict__ bp,
                             float* __restrict__ dout)
{
    int tid = blockIdx.x * blockDim.x + threadIdx.x;  // 0..8191
    if (tid >= 8192) return;
    int i  = tid & 31;
    int jj = (tid >> 5) & 31;
    int bo = tid >> 10;
    int o  = bo & 3;
    const float* src = of + (size_t)bo * SQ;
    int y = jj * 2, x = i * 2;
    float dval = 0.25f * (src[y * 64 + x] + src[y * 64 + x + 1] +
                          src[(y + 1) * 64 + x] + src[(y + 1) * 64 + x + 1]) + bp[o];
    dout[tid]        = sff[tid] + dval;
    dout[8192 + tid] = dval;
}

extern "C" void kernel_launch(void* const* d_in, const int* in_sizes, int n_in,
                              void* d_out, int out_size, void* d_ws, size_t ws_size,
                              hipStream_t stream)
{
    const float* second_frame = (const float*)d_in[0];
    const float* first_frame  = (const float*)d_in[1];
    const float* sff          = (const float*)d_in[2];
    const float* ffa          = (const float*)d_in[3];
    const float* Wq = (const float*)d_in[4];
    const float* bq = (const float*)d_in[5];
    const float* Wk = (const float*)d_in[6];
    const float* bk = (const float*)d_in[7];
    const float* Wv = (const float*)d_in[8];
    const float* bv = (const float*)d_in[9];
    const float* Wp = (const float*)d_in[10];
    const float* bp = (const float*)d_in[11];
    const float* Wt = (const float*)d_in[12];
    const float* bt = (const float*)d_in[13];
    float* out = (float*)d_out;

    char* ws = (char*)d_ws;
    const size_t QKV = (size_t)2 * NHEADS * SQ * D * sizeof(unsigned short);
    unsigned short* Qb = (unsigned short*)ws;
    unsigned short* Kb = (unsigned short*)(ws + QKV);
    unsigned short* Vt = (unsigned short*)(ws + 2 * QKV);
    float* tbuf = (float*)(ws + 3 * QKV);
    float* of   = (float*)(ws + 3 * QKV + (size_t)2 * NHEADS * SQ * sizeof(float));

    prep_kernel<<<1152, 256, 0, stream>>>(second_frame, first_frame, ffa,
                                          Wq, bq, Wk, bk, Wv, bv, Wt, bt,
                                          Qb, Kb, Vt, tbuf, of);
    dim3 ag(16, 18, ZSPLIT);
    attn_kernel<<<ag, 256, 0, stream>>>(Qb, Kb, Vt, tbuf, Wp, of);
    final_kernel<<<32, 256, 0, stream>>>(of, sff, bp, out);
}